// Round 1
// baseline (370.840 us; speedup 1.0000x reference)
//
#include <hip/hip_runtime.h>
#include <math.h>

#define NPTS   32768
#define NCODES 1024
#define DIM    256
#define HWSZ   1024            // H*W
#define CHW    (DIM*HWSZ)      // 262144, per-batch stride in z
#define QSZ    8388608         // B*C*H*W

// ws layout (floats):
//  [0,       262144) embT  (256 x 1024)
//  [262144,  263168) e2    (1024)
//  [263168,  394240) minv  (4 groups x 32768)
//  [394240,  525312) mini  (int, 4 x 32768)   -> total ~2.1 MB

// ---- kernel 1a: e2[k] = sum_c emb[k][c]^2  (fp64 accumulate) ----
__global__ void k_e2(const float* __restrict__ emb, float* __restrict__ e2) {
    int tid  = threadIdx.x;
    int lane = tid & 63;
    int w    = tid >> 6;
    int k    = blockIdx.x * 4 + w;
    const float4 v = *reinterpret_cast<const float4*>(emb + k * DIM + lane * 4);
    double s = (double)v.x * v.x + (double)v.y * v.y + (double)v.z * v.z + (double)v.w * v.w;
    #pragma unroll
    for (int m = 32; m >= 1; m >>= 1) s += __shfl_xor(s, m);
    if (lane == 0) e2[k] = (float)s;
}

// ---- kernel 1b: embT[c][k] = emb[k][c] ----
__global__ void k_transpose(const float* __restrict__ emb, float* __restrict__ embT) {
    __shared__ float T[64][65];
    int tid = threadIdx.x;
    int kt  = blockIdx.x & 15;   // code tile
    int ct  = blockIdx.x >> 4;   // dim tile
    int k0 = kt * 64, c0 = ct * 64;
    int cc = tid & 63, r0 = tid >> 6;
    #pragma unroll
    for (int i = 0; i < 16; ++i) {
        int r = r0 + i * 4;
        T[r][cc] = emb[(k0 + r) * DIM + c0 + cc];
    }
    __syncthreads();
    int kk = tid & 63, rr0 = tid >> 6;
    #pragma unroll
    for (int i = 0; i < 16; ++i) {
        int rr = rr0 + i * 4;
        embT[(c0 + rr) * NCODES + k0 + kk] = T[kk][rr];
    }
}

// ---- kernel 2: fused distance GEMM + argmin over a 256-code group ----
// grid: 256 point-tiles x 4 code-groups; block 256 threads; 8x8 reg tile.
__launch_bounds__(256, 2)
__global__ void k_dist(const float* __restrict__ z, const float* __restrict__ embT,
                       const float* __restrict__ e2, float* __restrict__ minv,
                       int* __restrict__ mini) {
    __shared__ float As[32][128];
    __shared__ float Bs[32][128];
    __shared__ float e2s[256];

    int tid = threadIdx.x;
    int pt  = blockIdx.x >> 2;
    int g   = blockIdx.x & 3;
    int n0  = pt * 128;                       // 128 | 1024 -> single batch b
    int b   = n0 >> 10, hw0 = n0 & 1023;
    const float* zp = z + b * CHW + hw0;

    int tx = tid & 15, ty = tid >> 4;
    int sc4 = (tid & 31) * 4;                 // staging column (float4)
    int sd0 = tid >> 5;                       // staging row base 0..7

    float bestv[8]; int besti[8];
    #pragma unroll
    for (int i = 0; i < 8; ++i) { bestv[i] = 3.4e38f; besti[i] = 0; }

    e2s[tid] = e2[g * 256 + tid];             // whole group's e2, used post-sync

    for (int kc = 0; kc < 2; ++kc) {
        int k0 = g * 256 + kc * 128;
        float acc[8][8];
        #pragma unroll
        for (int i = 0; i < 8; ++i)
            #pragma unroll
            for (int j = 0; j < 8; ++j) acc[i][j] = 0.f;

        for (int dc = 0; dc < 8; ++dc) {
            int d0 = dc * 32;
            __syncthreads();
            #pragma unroll
            for (int i = 0; i < 4; ++i) {
                int di = sd0 + i * 8;
                *reinterpret_cast<float4*>(&As[di][sc4]) =
                    *reinterpret_cast<const float4*>(zp + (d0 + di) * HWSZ + sc4);
                *reinterpret_cast<float4*>(&Bs[di][sc4]) =
                    *reinterpret_cast<const float4*>(embT + (d0 + di) * NCODES + k0 + sc4);
            }
            __syncthreads();
            #pragma unroll 4
            for (int d = 0; d < 32; ++d) {
                float4 a0 = *reinterpret_cast<const float4*>(&As[d][ty * 8]);
                float4 a1 = *reinterpret_cast<const float4*>(&As[d][ty * 8 + 4]);
                float4 b0 = *reinterpret_cast<const float4*>(&Bs[d][tx * 4]);
                float4 b1 = *reinterpret_cast<const float4*>(&Bs[d][64 + tx * 4]);
                float av[8] = {a0.x, a0.y, a0.z, a0.w, a1.x, a1.y, a1.z, a1.w};
                float bv[8] = {b0.x, b0.y, b0.z, b0.w, b1.x, b1.y, b1.z, b1.w};
                #pragma unroll
                for (int i = 0; i < 8; ++i)
                    #pragma unroll
                    for (int j = 0; j < 8; ++j)
                        acc[i][j] = fmaf(av[i], bv[j], acc[i][j]);
            }
        }
        // epilogue: dist = e2 - 2*dot; running min (ascending code -> first-min tiebreak)
        #pragma unroll
        for (int j = 0; j < 8; ++j) {
            int col  = (j < 4) ? (tx * 4 + j) : (64 + tx * 4 + (j - 4));
            float ev = e2s[kc * 128 + col];
            int code = k0 + col;
            #pragma unroll
            for (int i = 0; i < 8; ++i) {
                float dist = fmaf(-2.f, acc[i][j], ev);
                if (dist < bestv[i]) { bestv[i] = dist; besti[i] = code; }
            }
        }
    }
    // reduce across tx (16 lanes within the wave), lexicographic (val, idx)
    #pragma unroll
    for (int m = 1; m < 16; m <<= 1) {
        #pragma unroll
        for (int i = 0; i < 8; ++i) {
            float ov = __shfl_xor(bestv[i], m);
            int   oi = __shfl_xor(besti[i], m);
            if (ov < bestv[i] || (ov == bestv[i] && oi < besti[i])) {
                bestv[i] = ov; besti[i] = oi;
            }
        }
    }
    if (tx == 0) {
        #pragma unroll
        for (int i = 0; i < 8; ++i) {
            int n = n0 + ty * 8 + i;
            minv[g * NPTS + n] = bestv[i];
            mini[g * NPTS + n] = besti[i];
        }
    }
}

// ---- kernel 3: combine group winners, gather, write outputs ----
__global__ void k_out(const float* __restrict__ z, const float* __restrict__ emb,
                      const float* __restrict__ minv, const int* __restrict__ mini,
                      float* __restrict__ out) {
    int n = blockIdx.x * 64 + threadIdx.x;
    float bv = minv[n]; int bi = mini[n];
    #pragma unroll
    for (int gg = 1; gg < 4; ++gg) {
        float v = minv[gg * NPTS + n];
        int  ii = mini[gg * NPTS + n];
        if (v < bv) { bv = v; bi = ii; }       // ascending groups -> first-min tiebreak
    }
    out[2 * QSZ + n] = (float)bi;              // idx as float (harness reads fp32 flat)
    int b = n >> 10, hw = n & 1023;
    float*       q  = out + b * CHW + hw;
    float*       st = q + QSZ;
    const float* zq = z + b * CHW + hw;
    for (int c4 = 0; c4 < 64; ++c4) {
        float4 e4 = *reinterpret_cast<const float4*>(emb + bi * DIM + c4 * 4);
        float ev[4] = {e4.x, e4.y, e4.z, e4.w};
        #pragma unroll
        for (int j = 0; j < 4; ++j) {
            int off = (c4 * 4 + j) * HWSZ;
            float zv = zq[off];
            q[off]  = ev[j];
            st[off] = (ev[j] - zv) + zv;       // mimic reference rounding
        }
    }
}

extern "C" void kernel_launch(void* const* d_in, const int* in_sizes, int n_in,
                              void* d_out, int out_size, void* d_ws, size_t ws_size,
                              hipStream_t stream) {
    const float* z   = (const float*)d_in[0];
    const float* emb = (const float*)d_in[1];
    float* ws   = (float*)d_ws;
    float* embT = ws;                          // 262144 floats
    float* e2   = ws + 262144;                 // 1024
    float* minv = ws + 263168;                 // 131072
    int*   mini = (int*)(ws + 394240);         // 131072
    float* out  = (float*)d_out;

    hipLaunchKernelGGL(k_e2,        dim3(256),  dim3(256), 0, stream, emb, e2);
    hipLaunchKernelGGL(k_transpose, dim3(64),   dim3(256), 0, stream, emb, embT);
    hipLaunchKernelGGL(k_dist,      dim3(1024), dim3(256), 0, stream, z, embT, e2, minv, mini);
    hipLaunchKernelGGL(k_out,       dim3(512),  dim3(64),  0, stream, z, emb, minv, mini, out);
}

// Round 2
// 190.045 us; speedup vs baseline: 1.9513x; 1.9513x over previous
//
#include <hip/hip_runtime.h>

#define NPTS   32768
#define NCODES 1024
#define DIM    256
#define HWSZ   1024
#define CHW    (DIM*HWSZ)      // 262144
#define QSZ    8388608         // B*C*H*W

typedef __attribute__((ext_vector_type(8))) short short8;   // 8 bf16 = 4 VGPRs
typedef __attribute__((ext_vector_type(4))) float f32x4;

// async global->LDS, 16B per lane; dest = wave-uniform base + lane*16
__device__ __forceinline__ void gload16(const void* g, void* l) {
    __builtin_amdgcn_global_load_lds((const __attribute__((address_space(1))) void*)g,
                                     (__attribute__((address_space(3))) void*)l,
                                     16, 0, 0);
}

__device__ __forceinline__ unsigned bf16_rne(float f) {
    unsigned u = __float_as_uint(f);
    return (u + 0x7fffu + ((u >> 16) & 1u)) >> 16;
}

// ---- e2[k] = sum_c emb[k][c]^2 (fp64 accumulate; tiny) ----
__global__ void k_e2(const float* __restrict__ emb, float* __restrict__ e2) {
    int tid  = threadIdx.x;
    int lane = tid & 63;
    int w    = tid >> 6;
    int k    = blockIdx.x * 4 + w;
    const float4 v = *reinterpret_cast<const float4*>(emb + k * DIM + lane * 4);
    double s = (double)v.x * v.x + (double)v.y * v.y + (double)v.z * v.z + (double)v.w * v.w;
    #pragma unroll
    for (int m = 32; m >= 1; m >>= 1) s += __shfl_xor(s, m);
    if (lane == 0) e2[k] = (float)s;
}

// ---- emb (1024x256 f32) -> Eh, El bf16 bit patterns, same row-major layout ----
__global__ void k_prep_e(const float* __restrict__ emb, short* __restrict__ Eh,
                         short* __restrict__ El) {
    int idx = blockIdx.x * 256 + threadIdx.x;          // 65536 threads x float4
    float4 v = reinterpret_cast<const float4*>(emb)[idx];
    float f[4] = {v.x, v.y, v.z, v.w};
    short h[4], l[4];
    #pragma unroll
    for (int i = 0; i < 4; ++i) {
        unsigned hb = bf16_rne(f[i]);
        float hf = __uint_as_float(hb << 16);
        h[i] = (short)hb;
        l[i] = (short)bf16_rne(f[i] - hf);
    }
    reinterpret_cast<short4*>(Eh)[idx] = make_short4(h[0], h[1], h[2], h[3]);
    reinterpret_cast<short4*>(El)[idx] = make_short4(l[0], l[1], l[2], l[3]);
}

// ---- z (b,c,hw) f32 -> Xh, Xl row-major (n = b*1024+hw, c) bf16 hi/lo ----
__global__ void k_prep_x(const float* __restrict__ z, short* __restrict__ Xh,
                         short* __restrict__ Xl) {
    __shared__ float T[64][65];
    int blk = blockIdx.x;            // 32 b x 4 ctiles x 16 hwtiles = 2048
    int b   = blk >> 6;
    int ct  = (blk >> 4) & 3;
    int ht  = blk & 15;
    int c0 = ct * 64, hw0 = ht * 64;
    int tid = threadIdx.x;
    int cc = tid & 63, r0 = tid >> 6;
    const float* zp = z + b * CHW;
    #pragma unroll
    for (int i = 0; i < 16; ++i) {
        int r = r0 + i * 4;                          // c_local
        T[r][cc] = zp[(c0 + r) * HWSZ + hw0 + cc];   // coalesced read
    }
    __syncthreads();
    int cl = tid & 63;
    #pragma unroll
    for (int i = 0; i < 16; ++i) {
        int hwl = r0 + i * 4;                        // hw_local
        float f = T[cl][hwl];                        // stride-65: conflict-free
        unsigned hb = bf16_rne(f);
        float hf = __uint_as_float(hb << 16);
        unsigned lb = bf16_rne(f - hf);
        int n = b * HWSZ + hw0 + hwl;
        Xh[n * DIM + c0 + cl] = (short)hb;           // coalesced 128B writes
        Xl[n * DIM + c0 + cl] = (short)lb;
    }
}

// ---- fused split-bf16 MFMA distance GEMM + argmin over a 128-code tile ----
// grid: 256 pt-tiles x 8 code-tiles; block 256 threads (4 waves, 2x2 wave grid).
// virtual K = 768: seg0 Xh*Eh, seg1 Xh*El, seg2 Xl*Eh.
__launch_bounds__(256, 2)
__global__ void k_dist(const short* __restrict__ Xh, const short* __restrict__ Xl,
                       const short* __restrict__ Eh, const short* __restrict__ El,
                       const float* __restrict__ e2, float* __restrict__ minv,
                       int* __restrict__ mini) {
    __shared__ __align__(16) short As[4096];   // [128 pts][32 k] bf16
    __shared__ __align__(16) short Bs[4096];   // [128 codes][32 k] bf16
    __shared__ float sv[2][128];
    __shared__ int   si[2][128];

    const int tid = threadIdx.x;
    const int ct = blockIdx.x & 7;
    const int pt = blockIdx.x >> 3;
    const int n0 = pt * 128;
    const int c0 = ct * 128;

    const int w = tid >> 6, lane = tid & 63;
    const int wr = w >> 1, wc = w & 1;              // wave covers pts wr*64, codes wc*64
    const int m16 = lane & 15, quad = lane >> 4;

    f32x4 acc[4][4];
    #pragma unroll
    for (int i = 0; i < 4; ++i)
        #pragma unroll
        for (int j = 0; j < 4; ++j) acc[i][j] = (f32x4){0.f, 0.f, 0.f, 0.f};

    const int row = tid >> 2;          // tile row this thread stages (0..63)
    const int ks  = (tid & 3) * 8;     // short offset within 32-wide k row

    char* aDst0 = (char*)As + w * 1024;          // lane*16 appended by HW
    char* aDst1 = (char*)As + 4096 + w * 1024;
    char* bDst0 = (char*)Bs + w * 1024;
    char* bDst1 = (char*)Bs + 4096 + w * 1024;

    for (int t = 0; t < 24; ++t) {
        const int seg  = t >> 3;
        const int koff = (t & 7) * 32 + ks;
        const short* Asrc = (seg == 2) ? Xl : Xh;
        const short* Bsrc = (seg == 1) ? El : Eh;
        __syncthreads();
        gload16(Asrc + (n0 + row) * DIM + koff,      aDst0);
        gload16(Asrc + (n0 + 64 + row) * DIM + koff, aDst1);
        gload16(Bsrc + (c0 + row) * DIM + koff,      bDst0);
        gload16(Bsrc + (c0 + 64 + row) * DIM + koff, bDst1);
        __syncthreads();                 // compiler drains vmcnt before barrier

        short8 af[4], bf[4];
        #pragma unroll
        for (int i = 0; i < 4; ++i)
            af[i] = *(const short8*)&As[(wr * 64 + i * 16 + m16) * 32 + quad * 8];
        #pragma unroll
        for (int j = 0; j < 4; ++j)
            bf[j] = *(const short8*)&Bs[(wc * 64 + j * 16 + m16) * 32 + quad * 8];
        #pragma unroll
        for (int i = 0; i < 4; ++i)
            #pragma unroll
            for (int j = 0; j < 4; ++j)
                acc[i][j] = __builtin_amdgcn_mfma_f32_16x16x32_bf16(af[i], bf[j], acc[i][j], 0, 0, 0);
    }

    // dist = e2[code] - 2*dot ; C/D layout: col=lane&15 (code), row=quad*4+reg (point)
    float ecol[4];
    #pragma unroll
    for (int j = 0; j < 4; ++j) ecol[j] = e2[c0 + wc * 64 + j * 16 + m16];

    #pragma unroll
    for (int i = 0; i < 4; ++i) {
        #pragma unroll
        for (int r = 0; r < 4; ++r) {
            float best = 3.4e38f; int bi = 0;
            #pragma unroll
            for (int j = 0; j < 4; ++j) {           // j ascending -> code ascending
                float d = fmaf(-2.f, acc[i][j][r], ecol[j]);
                int code = c0 + wc * 64 + j * 16 + m16;
                if (d < best) { best = d; bi = code; }
            }
            #pragma unroll
            for (int m = 1; m < 16; m <<= 1) {      // 16 lanes hold 16 codes of this point
                float ov = __shfl_xor(best, m);
                int   oi = __shfl_xor(bi, m);
                if (ov < best || (ov == best && oi < bi)) { best = ov; bi = oi; }
            }
            if (m16 == 0) {
                int p = wr * 64 + i * 16 + quad * 4 + r;
                sv[wc][p] = best; si[wc][p] = bi;
            }
        }
    }
    __syncthreads();
    if (tid < 128) {
        float v0 = sv[0][tid]; int i0 = si[0][tid];
        float v1 = sv[1][tid]; int i1 = si[1][tid];
        if (v1 < v0) { v0 = v1; i0 = i1; }          // tie -> wc0 = smaller codes
        minv[ct * NPTS + n0 + tid] = v0;
        mini[ct * NPTS + n0 + tid] = i0;
    }
}

// ---- combine 8 code-tile winners per point ----
__global__ void k_argmin(const float* __restrict__ minv, const int* __restrict__ mini,
                         int* __restrict__ idxw, float* __restrict__ idxf) {
    int n = blockIdx.x * 256 + threadIdx.x;
    float bv = minv[n]; int bi = mini[n];
    #pragma unroll
    for (int g = 1; g < 8; ++g) {
        float v = minv[g * NPTS + n]; int ii = mini[g * NPTS + n];
        if (v < bv) { bv = v; bi = ii; }            // ascending groups -> first-min
    }
    idxw[n] = bi;
    idxf[n] = (float)bi;
}

// ---- gather + write q, st (fp32 exact from emb) ----
__global__ void k_out2(const float* __restrict__ z, const float* __restrict__ emb,
                       const int* __restrict__ idx, float* __restrict__ out) {
    int tid = threadIdx.x;
    int n  = blockIdx.x * 32 + (tid & 31);          // 1024 blocks x 32 points
    int ch = tid >> 5;                              // 8 channel-chunks of 32
    int bi = idx[n];
    int b = n >> 10, hw = n & 1023;
    const float* ep = emb + bi * DIM + ch * 32;
    int base = b * CHW + (ch * 32) * HWSZ + hw;
    #pragma unroll 8
    for (int c = 0; c < 32; ++c) {
        float ev = ep[c];
        int off = base + c * HWSZ;
        float zv = z[off];
        out[off] = ev;
        out[QSZ + off] = (ev - zv) + zv;            // mimic reference rounding
    }
}

extern "C" void kernel_launch(void* const* d_in, const int* in_sizes, int n_in,
                              void* d_out, int out_size, void* d_ws, size_t ws_size,
                              hipStream_t stream) {
    const float* z   = (const float*)d_in[0];
    const float* emb = (const float*)d_in[1];
    float* out = (float*)d_out;
    float* ws  = (float*)d_ws;

    // ws layout (floats): Eh[0,131072) El[131072,262144) e2[262144,263168)
    //                     minv[263168,525312) mini[525312,787456) idx[787456,820224)
    short* Eh   = (short*)ws;
    short* El   = (short*)(ws + 131072);
    float* e2   = ws + 262144;
    float* minv = ws + 263168;
    int*   mini = (int*)(ws + 525312);
    int*   idxw = (int*)(ws + 787456);

    // big X arrays live in d_out's q/st region (fully overwritten by k_out2 later)
    short* Xh = (short*)out;                 // 16.8 MB
    short* Xl = (short*)(out + 4194304);     // 16.8 MB
    float* idxf = out + 2 * QSZ;

    hipLaunchKernelGGL(k_prep_e, dim3(256),  dim3(256), 0, stream, emb, Eh, El);
    hipLaunchKernelGGL(k_e2,     dim3(256),  dim3(256), 0, stream, emb, e2);
    hipLaunchKernelGGL(k_prep_x, dim3(2048), dim3(256), 0, stream, z, Xh, Xl);
    hipLaunchKernelGGL(k_dist,   dim3(2048), dim3(256), 0, stream, Xh, Xl, Eh, El, e2, minv, mini);
    hipLaunchKernelGGL(k_argmin, dim3(128),  dim3(256), 0, stream, minv, mini, idxw, idxf);
    hipLaunchKernelGGL(k_out2,   dim3(1024), dim3(256), 0, stream, z, emb, idxw, out);
}